// Round 1
// baseline (561.523 us; speedup 1.0000x reference)
//
#include <hip/hip_runtime.h>
#include <math.h>

typedef __attribute__((ext_vector_type(8))) short short8;
typedef __attribute__((ext_vector_type(4))) float f32x4;
typedef unsigned short u16;
typedef unsigned int u32;
typedef unsigned long long u64;

static constexpr int E = 1024, H = 16, LQ = 1024, LC = 512, Bn = 4, FF = 4096;
static constexpr int NTOK = Bn * LQ;   // 4096
static constexpr int NCTX = Bn * LC;   // 2048

// ---------------- workspace layout (bytes) ----------------
static constexpr size_t OFF_TCOS   = 0;                                    // 1024*32 f32
static constexpr size_t OFF_TSIN   = OFF_TCOS + (size_t)LQ*32*4;
static constexpr size_t OFF_BSAQKV = OFF_TSIN + (size_t)LQ*32*4;           // 3072 f32
static constexpr size_t OFF_BCAKV  = OFF_BSAQKV + 16384;                   // 2048 f32
static constexpr size_t OFF_WSAQKV = OFF_BCAKV + 16384;                    // [3072][1024] bf16
static constexpr size_t OFF_WSAP   = OFF_WSAQKV + (size_t)3072*1024*2;     // [1024][1024]
static constexpr size_t OFF_WCAQ   = OFF_WSAP   + (size_t)1024*1024*2;
static constexpr size_t OFF_WCAKV  = OFF_WCAQ   + (size_t)1024*1024*2;     // [2048][1024]
static constexpr size_t OFF_WCAP   = OFF_WCAKV  + (size_t)2048*1024*2;
static constexpr size_t OFF_WFC1   = OFF_WCAP   + (size_t)1024*1024*2;     // [4096][1024]
static constexpr size_t OFF_WFC2   = OFF_WFC1   + (size_t)4096*1024*2;     // [1024][4096]
static constexpr size_t OFF_CTXB   = OFF_WFC2   + (size_t)1024*4096*2;     // [2048][1024] bf16
static constexpr size_t OFF_H      = OFF_CTXB   + (size_t)2048*1024*2;     // [4096][1024] bf16 (LN out)
static constexpr size_t OFF_QKV    = OFF_H      + (size_t)4096*1024*2;     // [4096][3072] bf16
static constexpr size_t OFF_CAQ    = OFF_QKV;                              // [4096][1024]
static constexpr size_t OFF_CAKV   = OFF_QKV + (size_t)4096*1024*2;        // [2048][2048]
static constexpr size_t OFF_QR     = OFF_QKV + (size_t)4096*3072*2;        // [B,H,LQ,64]
static constexpr size_t OFF_KR     = OFF_QR  + (size_t)4096*1024*2;        // [B,H,Lk,64]
static constexpr size_t OFF_VT     = OFF_KR  + (size_t)4096*1024*2;        // [B,H,64,Lk]
static constexpr size_t OFF_AO     = OFF_VT  + (size_t)4096*1024*2;        // [4096][1024] bf16
static constexpr size_t OFF_U      = OFF_QKV;                              // fc1 out [4096][4096] bf16 reuses QKV+QR
static constexpr size_t WS_NEED    = OFF_AO + (size_t)4096*1024*2;         // ~105 MB

// ---------------- helpers ----------------
static __device__ __forceinline__ float bf2f(u16 u) {
  union { u32 i; float f; } un; un.i = ((u32)u) << 16; return un.f;
}
static __device__ __forceinline__ u16 f2bf(float f) {  // RNE
  union { float f; u32 u; } un; un.f = f;
  u32 u = un.u;
  return (u16)((u + 0x7FFFu + ((u >> 16) & 1u)) >> 16);
}
static __device__ __forceinline__ u64 pack4(u16 a, u16 b, u16 c, u16 d) {
  return (u64)a | ((u64)b << 16) | ((u64)c << 32) | ((u64)d << 48);
}
static __device__ __forceinline__ f32x4 mfma16(short8 a, short8 b, f32x4 c) {
  return __builtin_amdgcn_mfma_f32_16x16x32_bf16(a, b, c, 0, 0, 0);
}
static __device__ __forceinline__ void gload_lds16(void* lds, const void* g) {
  __builtin_amdgcn_global_load_lds(
      (const __attribute__((address_space(1))) void*)g,
      (__attribute__((address_space(3))) void*)lds, 16, 0, 0);
}
static __device__ __forceinline__ float gelu_tanh(float x) {
  float t = tanhf(0.7978845608028654f * (x + 0.044715f * x * x * x));
  return 0.5f * x * (1.0f + t);
}

// ---------------- small kernels ----------------
__global__ __launch_bounds__(256) void build_tab(float* __restrict__ ct, float* __restrict__ st) {
  int idx = blockIdx.x * 256 + threadIdx.x;           // 1024*32 entries
  int pos = idx >> 5, i = idx & 31;
  float inv = powf(10000.f, -(float)i * (1.f / 32.f));
  float a = (float)pos * inv;
  ct[idx] = cosf(a);
  st[idx] = sinf(a);
}

__global__ __launch_bounds__(256) void cvt_bf16(const float* __restrict__ src, u16* __restrict__ dst, int n) {
  int i = (blockIdx.x * 256 + threadIdx.x) * 4;
  if (i + 3 < n) {
    float4 v = *(const float4*)(src + i);
    *(u64*)(dst + i) = pack4(f2bf(v.x), f2bf(v.y), f2bf(v.z), f2bf(v.w));
  }
}

__global__ __launch_bounds__(256) void copy_f32(const float* __restrict__ src, float* __restrict__ dst, int n) {
  int i = blockIdx.x * 256 + threadIdx.x;
  if (i < n) dst[i] = src[i];
}

// LN over last dim 1024, one row per block (256 threads, 4 f32 each), bf16 out.
__global__ __launch_bounds__(256) void ln_bf16(const float* __restrict__ x, const float* __restrict__ w,
                                               const float* __restrict__ b, u16* __restrict__ out) {
  __shared__ float red[4];
  int row = blockIdx.x, tid = threadIdx.x;
  const float* xr = x + (size_t)row * 1024;
  float4 v = ((const float4*)xr)[tid];
  float s = v.x + v.y + v.z + v.w;
#pragma unroll
  for (int off = 32; off; off >>= 1) s += __shfl_xor(s, off);
  if ((tid & 63) == 0) red[tid >> 6] = s;
  __syncthreads();
  float mean = (red[0] + red[1] + red[2] + red[3]) * (1.f / 1024.f);
  float dx = v.x - mean, dy = v.y - mean, dz = v.z - mean, dw = v.w - mean;
  float sq = dx * dx + dy * dy + dz * dz + dw * dw;
#pragma unroll
  for (int off = 32; off; off >>= 1) sq += __shfl_xor(sq, off);
  __syncthreads();
  if ((tid & 63) == 0) red[tid >> 6] = sq;
  __syncthreads();
  float var = (red[0] + red[1] + red[2] + red[3]) * (1.f / 1024.f);
  float rstd = rsqrtf(var + 1e-6f);
  float4 wv = ((const float4*)w)[tid];
  float4 bv = ((const float4*)b)[tid];
  u64 o = pack4(f2bf(dx * rstd * wv.x + bv.x), f2bf(dy * rstd * wv.y + bv.y),
                f2bf(dz * rstd * wv.z + bv.z), f2bf(dw * rstd * wv.w + bv.w));
  *(u64*)(out + (size_t)row * 1024 + tid * 4) = o;
}

// RoPE + layout scatter. src [T][ld] bf16 (+col0), 128 threads x 8 elems per token.
// ROPE=1: rotate pairs, dst [B,H,Lper,64]. TRANS=1: no rope, dst [B,H,64,Lper] (for V).
template <int ROPE, int TRANS>
__global__ __launch_bounds__(128) void rope_scatter(const u16* __restrict__ src, int ld, int col0,
                                                    u16* __restrict__ dst,
                                                    const float* __restrict__ cosT,
                                                    const float* __restrict__ sinT, int Lper) {
  int t = blockIdx.x;
  int b = t / Lper, l = t - b * Lper;
  int tid = threadIdx.x;
  int e0 = tid * 8;
  int h = e0 >> 6, d0 = e0 & 63;
  short8 vv = *(const short8*)(src + (size_t)t * ld + col0 + e0);
  if (ROPE) {
    short8 ov;
#pragma unroll
    for (int j = 0; j < 4; ++j) {
      float x1 = bf2f((u16)vv[2 * j]);
      float x2 = bf2f((u16)vv[2 * j + 1]);
      int i = (d0 >> 1) + j;
      float c = cosT[l * 32 + i], s = sinT[l * 32 + i];
      ov[2 * j]     = (short)f2bf(x1 * c - x2 * s);
      ov[2 * j + 1] = (short)f2bf(x1 * s + x2 * c);
    }
    *(short8*)(dst + (((size_t)b * H + h) * Lper + l) * 64 + d0) = ov;
  } else if (TRANS) {
#pragma unroll
    for (int m = 0; m < 8; ++m)
      dst[(((size_t)b * H + h) * 64 + d0 + m) * Lper + l] = (u16)vv[m];
  }
}

// ---------------- GEMM: C[M,N] = A[M,K] @ W[N,K]^T + bias, bf16 in / f32 acc ----------------
enum { EPI_BF16 = 0, EPI_GELU = 1, EPI_RESID = 2 };

template <int EPI>
__global__ __launch_bounds__(256, 2) void gemm_bt(const u16* __restrict__ A, const u16* __restrict__ W,
                                                  const float* __restrict__ bias, u16* outb, float* outf,
                                                  const float* res, const float* __restrict__ gate,
                                                  int M, int N, int K) {
  __shared__ u16 As[128 * 64];
  __shared__ u16 Bs[128 * 64];

  // bijective XCD swizzle (all our grids have nwg % 8 == 0)
  int nwg = gridDim.x * gridDim.y;
  int bid = blockIdx.y * gridDim.x + blockIdx.x;
  int cpx = nwg >> 3;
  int swz = (bid & 7) * cpx + (bid >> 3);
  int bx = swz % gridDim.x;
  int by = swz / gridDim.x;
  int row0 = by * 128, col0 = bx * 128;

  int tid = threadIdx.x;
  int lane = tid & 63, wid = tid >> 6;
  int wr = wid >> 1, wc = wid & 1;  // 2x2 waves, each owns 64x64
  int lr = lane & 15, lg = lane >> 4;

  f32x4 acc[4][4] = {};

  const int nkt = K >> 6;
  for (int kt = 0; kt < nkt; ++kt) {
    int k0 = kt << 6;
    // stage 16 KB A + 16 KB B; LDS linear, global source pre-swizzled (chunk p^(r&7))
#pragma unroll
    for (int j = 0; j < 4; ++j) {
      int q = j * 256 + tid;           // chunk id 0..1023 (16B chunks)
      int r = q >> 3, p = q & 7;
      int sp = p ^ (r & 7);
      gload_lds16(As + (size_t)(j * 256 + wid * 64) * 8, A + (size_t)(row0 + r) * K + k0 + sp * 8);
      gload_lds16(Bs + (size_t)(j * 256 + wid * 64) * 8, W + (size_t)(col0 + r) * K + k0 + sp * 8);
    }
    __syncthreads();
#pragma unroll
    for (int kk = 0; kk < 2; ++kk) {
      short8 af[4], bf[4];
#pragma unroll
      for (int m = 0; m < 4; ++m) {
        int r = wr * 64 + m * 16 + lr;
        int sc = (kk * 4 + lg) ^ (r & 7);
        af[m] = *(const short8*)(As + r * 64 + sc * 8);
      }
#pragma unroll
      for (int n = 0; n < 4; ++n) {
        int r = wc * 64 + n * 16 + lr;
        int sc = (kk * 4 + lg) ^ (r & 7);
        bf[n] = *(const short8*)(Bs + r * 64 + sc * 8);
      }
#pragma unroll
      for (int m = 0; m < 4; ++m)
#pragma unroll
        for (int n = 0; n < 4; ++n)
          acc[m][n] = mfma16(af[m], bf[n], acc[m][n]);
    }
    __syncthreads();
  }

  // epilogue: C layout col=lane&15, row=(lane>>4)*4+i
#pragma unroll
  for (int n = 0; n < 4; ++n) {
    int cg = col0 + wc * 64 + n * 16 + lr;
    float bv = bias[cg];
#pragma unroll
    for (int m = 0; m < 4; ++m) {
#pragma unroll
      for (int i = 0; i < 4; ++i) {
        int rg = row0 + wr * 64 + m * 16 + lg * 4 + i;
        float v = acc[m][n][i] + bv;
        if (EPI == EPI_BF16) {
          outb[(size_t)rg * N + cg] = f2bf(v);
        } else if (EPI == EPI_GELU) {
          outb[(size_t)rg * N + cg] = f2bf(gelu_tanh(v));
        } else {
          float r = res[(size_t)rg * N + cg];
          outf[(size_t)rg * N + cg] = r + gate[cg] * v;
        }
      }
    }
  }
}

// ---------------- flash attention ----------------
// Q [BH,Lq,64], K [BH,Lk,64], Vt [BH,64,Lk] (all bf16); out token-major [B,Lq,E] bf16.
// 1 wave per 16 Q rows; KV tiles of 32.
template <int CAUSAL>
__global__ __launch_bounds__(64) void flash_attn(const u16* __restrict__ Q, const u16* __restrict__ K,
                                                 const u16* __restrict__ Vt, u16* __restrict__ O,
                                                 int Lq, int Lk) {
  __shared__ u16 Pl[16 * 40];  // padded P tile
  const int bh = blockIdx.y;
  const int q0 = blockIdx.x * 16;
  const int lane = threadIdx.x;
  const int lr = lane & 15, lg = lane >> 4;

  const u16* Qb = Q + ((size_t)bh * Lq + q0) * 64;
  short8 aq0 = *(const short8*)(Qb + lr * 64 + lg * 8);
  short8 aq1 = *(const short8*)(Qb + lr * 64 + 32 + lg * 8);

  const u16* Kb = K + (size_t)bh * Lk * 64;
  const u16* Vb = Vt + (size_t)bh * 64 * Lk;

  f32x4 o[4] = {};
  float mrun[4], lrun[4];
#pragma unroll
  for (int i = 0; i < 4; ++i) { mrun[i] = -INFINITY; lrun[i] = 0.f; }

  const int ntile = CAUSAL ? ((q0 + 47) >> 5) : (Lk >> 5);
  for (int kt = 0; kt < ntile; ++kt) {
    int kbase = kt * 32;
    f32x4 s0 = {0, 0, 0, 0}, s1 = {0, 0, 0, 0};
    short8 bk;
    bk = *(const short8*)(Kb + (size_t)(kbase + lr) * 64 + lg * 8);
    s0 = mfma16(aq0, bk, s0);
    bk = *(const short8*)(Kb + (size_t)(kbase + lr) * 64 + 32 + lg * 8);
    s0 = mfma16(aq1, bk, s0);
    bk = *(const short8*)(Kb + (size_t)(kbase + 16 + lr) * 64 + lg * 8);
    s1 = mfma16(aq0, bk, s1);
    bk = *(const short8*)(Kb + (size_t)(kbase + 16 + lr) * 64 + 32 + lg * 8);
    s1 = mfma16(aq1, bk, s1);

    float al[4];
#pragma unroll
    for (int i = 0; i < 4; ++i) {
      float a = s0[i] * 0.125f, b2 = s1[i] * 0.125f;
      if (CAUSAL) {
        int rg = q0 + lg * 4 + i;
        if (kbase + lr > rg) a = -INFINITY;
        if (kbase + 16 + lr > rg) b2 = -INFINITY;
      }
      s0[i] = a; s1[i] = b2;
      float t = fmaxf(a, b2);
      t = fmaxf(t, __shfl_xor(t, 1));
      t = fmaxf(t, __shfl_xor(t, 2));
      t = fmaxf(t, __shfl_xor(t, 4));
      t = fmaxf(t, __shfl_xor(t, 8));
      float mn = fmaxf(mrun[i], t);
      al[i] = __expf(mrun[i] - mn);
      mrun[i] = mn;
    }
    __syncthreads();  // WAR: previous tile's LDS reads done before overwrite
#pragma unroll
    for (int i = 0; i < 4; ++i) {
      float p0 = __expf(s0[i] - mrun[i]);
      float p1 = __expf(s1[i] - mrun[i]);
      Pl[(lg * 4 + i) * 40 + lr] = f2bf(p0);
      Pl[(lg * 4 + i) * 40 + 16 + lr] = f2bf(p1);
      float su = p0 + p1;
      su += __shfl_xor(su, 1);
      su += __shfl_xor(su, 2);
      su += __shfl_xor(su, 4);
      su += __shfl_xor(su, 8);
      lrun[i] = lrun[i] * al[i] + su;
      o[0][i] *= al[i]; o[1][i] *= al[i]; o[2][i] *= al[i]; o[3][i] *= al[i];
    }
    __syncthreads();
    short8 ap = *(const short8*)(Pl + lr * 40 + lg * 8);
#pragma unroll
    for (int nt = 0; nt < 4; ++nt) {
      short8 bv = *(const short8*)(Vb + (size_t)(nt * 16 + lr) * Lk + kbase + lg * 8);
      o[nt] = mfma16(ap, bv, o[nt]);
    }
  }

  int b = bh >> 4, h = bh & 15;
#pragma unroll
  for (int nt = 0; nt < 4; ++nt) {
#pragma unroll
    for (int i = 0; i < 4; ++i) {
      int rg = q0 + lg * 4 + i;
      O[((size_t)b * Lq + rg) * 1024 + h * 64 + nt * 16 + lr] = f2bf(o[nt][i] / lrun[i]);
    }
  }
}

// ---------------- launch ----------------
extern "C" void kernel_launch(void* const* d_in, const int* in_sizes, int n_in,
                              void* d_out, int out_size, void* d_ws, size_t ws_size,
                              hipStream_t stream) {
  (void)in_sizes; (void)n_in; (void)out_size;
  if (ws_size < WS_NEED) return;  // need ~105 MB scratch

  const float* x     = (const float*)d_in[0];
  const float* ctx   = (const float*)d_in[1];
  const float* g_msa = (const float*)d_in[3];
  const float* g_ca  = (const float*)d_in[4];
  const float* g_mlp = (const float*)d_in[5];
  const float* n1w = (const float*)d_in[6],  *n1b = (const float*)d_in[7];
  const float* n2w = (const float*)d_in[8],  *n2b = (const float*)d_in[9];
  const float* n3w = (const float*)d_in[10], *n3b = (const float*)d_in[11];
  const float* sa_qw = (const float*)d_in[12], *sa_kw = (const float*)d_in[14];
  const float* sa_vw = (const float*)d_in[16], *sa_pw = (const float*)d_in[18];
  const float* sa_qb = (const float*)d_in[13], *sa_kb = (const float*)d_in[15];
  const float* sa_vb = (const float*)d_in[17], *sa_pb = (const float*)d_in[19];
  const float* ca_qw = (const float*)d_in[20], *ca_qb = (const float*)d_in[21];
  const float* ca_kw = (const float*)d_in[22], *ca_kb = (const float*)d_in[23];
  const float* ca_vw = (const float*)d_in[24], *ca_vb = (const float*)d_in[25];
  const float* ca_pw = (const float*)d_in[26], *ca_pb = (const float*)d_in[27];
  const float* fc1w = (const float*)d_in[28], *fc1b = (const float*)d_in[29];
  const float* fc2w = (const float*)d_in[30], *fc2b = (const float*)d_in[31];

  char* ws = (char*)d_ws;
  float* out = (float*)d_out;
  float* tcos = (float*)(ws + OFF_TCOS);
  float* tsin = (float*)(ws + OFF_TSIN);
  u16* Hb   = (u16*)(ws + OFF_H);
  u16* QKV  = (u16*)(ws + OFF_QKV);
  u16* QR   = (u16*)(ws + OFF_QR);
  u16* KR   = (u16*)(ws + OFF_KR);
  u16* VT   = (u16*)(ws + OFF_VT);
  u16* AO   = (u16*)(ws + OFF_AO);

  // RoPE tables
  build_tab<<<dim3(128), dim3(256), 0, stream>>>(tcos, tsin);

  // weight/context conversion (fp32 -> bf16), QKV / KV concat layouts
  auto cvt = [&](const float* s, size_t byte_off, int n) {
    cvt_bf16<<<dim3(n / 1024), dim3(256), 0, stream>>>(s, (u16*)(ws + byte_off), n);
  };
  cvt(sa_qw, OFF_WSAQKV, 1024 * 1024);
  cvt(sa_kw, OFF_WSAQKV + (size_t)1024 * 1024 * 2, 1024 * 1024);
  cvt(sa_vw, OFF_WSAQKV + (size_t)2048 * 1024 * 2, 1024 * 1024);
  cvt(sa_pw, OFF_WSAP, 1024 * 1024);
  cvt(ca_qw, OFF_WCAQ, 1024 * 1024);
  cvt(ca_kw, OFF_WCAKV, 1024 * 1024);
  cvt(ca_vw, OFF_WCAKV + (size_t)1024 * 1024 * 2, 1024 * 1024);
  cvt(ca_pw, OFF_WCAP, 1024 * 1024);
  cvt(fc1w, OFF_WFC1, 4096 * 1024);
  cvt(fc2w, OFF_WFC2, 1024 * 4096);
  cvt(ctx, OFF_CTXB, NCTX * 1024);
  copy_f32<<<dim3(4), dim3(256), 0, stream>>>(sa_qb, (float*)(ws + OFF_BSAQKV), 1024);
  copy_f32<<<dim3(4), dim3(256), 0, stream>>>(sa_kb, (float*)(ws + OFF_BSAQKV + 4096), 1024);
  copy_f32<<<dim3(4), dim3(256), 0, stream>>>(sa_vb, (float*)(ws + OFF_BSAQKV + 8192), 1024);
  copy_f32<<<dim3(4), dim3(256), 0, stream>>>(ca_kb, (float*)(ws + OFF_BCAKV), 1024);
  copy_f32<<<dim3(4), dim3(256), 0, stream>>>(ca_vb, (float*)(ws + OFF_BCAKV + 4096), 1024);

  // ---- self-attention ----
  ln_bf16<<<dim3(NTOK), dim3(256), 0, stream>>>(x, n1w, n1b, Hb);
  gemm_bt<EPI_BF16><<<dim3(3072 / 128, NTOK / 128), dim3(256), 0, stream>>>(
      Hb, (u16*)(ws + OFF_WSAQKV), (float*)(ws + OFF_BSAQKV), QKV, nullptr, nullptr, nullptr,
      NTOK, 3072, 1024);
  rope_scatter<1, 0><<<dim3(NTOK), dim3(128), 0, stream>>>(QKV, 3072, 0, QR, tcos, tsin, LQ);
  rope_scatter<1, 0><<<dim3(NTOK), dim3(128), 0, stream>>>(QKV, 3072, 1024, KR, tcos, tsin, LQ);
  rope_scatter<0, 1><<<dim3(NTOK), dim3(128), 0, stream>>>(QKV, 3072, 2048, VT, tcos, tsin, LQ);
  flash_attn<1><<<dim3(LQ / 16, Bn * H), dim3(64), 0, stream>>>(QR, KR, VT, AO, LQ, LQ);
  gemm_bt<EPI_RESID><<<dim3(1024 / 128, NTOK / 128), dim3(256), 0, stream>>>(
      AO, (u16*)(ws + OFF_WSAP), sa_pb, nullptr, out, x, g_msa, NTOK, 1024, 1024);

  // ---- cross-attention ----
  ln_bf16<<<dim3(NTOK), dim3(256), 0, stream>>>(out, n2w, n2b, Hb);
  gemm_bt<EPI_BF16><<<dim3(1024 / 128, NTOK / 128), dim3(256), 0, stream>>>(
      Hb, (u16*)(ws + OFF_WCAQ), ca_qb, (u16*)(ws + OFF_CAQ), nullptr, nullptr, nullptr,
      NTOK, 1024, 1024);
  gemm_bt<EPI_BF16><<<dim3(2048 / 128, NCTX / 128), dim3(256), 0, stream>>>(
      (u16*)(ws + OFF_CTXB), (u16*)(ws + OFF_WCAKV), (float*)(ws + OFF_BCAKV),
      (u16*)(ws + OFF_CAKV), nullptr, nullptr, nullptr, NCTX, 2048, 1024);
  rope_scatter<1, 0><<<dim3(NTOK), dim3(128), 0, stream>>>((u16*)(ws + OFF_CAQ), 1024, 0, QR, tcos, tsin, LQ);
  rope_scatter<1, 0><<<dim3(NCTX), dim3(128), 0, stream>>>((u16*)(ws + OFF_CAKV), 2048, 0, KR, tcos, tsin, LC);
  rope_scatter<0, 1><<<dim3(NCTX), dim3(128), 0, stream>>>((u16*)(ws + OFF_CAKV), 2048, 1024, VT, tcos, tsin, LC);
  flash_attn<0><<<dim3(LQ / 16, Bn * H), dim3(64), 0, stream>>>(QR, KR, VT, AO, LQ, LC);
  gemm_bt<EPI_RESID><<<dim3(1024 / 128, NTOK / 128), dim3(256), 0, stream>>>(
      AO, (u16*)(ws + OFF_WCAP), ca_pb, nullptr, out, out, g_ca, NTOK, 1024, 1024);

  // ---- MLP ----
  ln_bf16<<<dim3(NTOK), dim3(256), 0, stream>>>(out, n3w, n3b, Hb);
  gemm_bt<EPI_GELU><<<dim3(4096 / 128, NTOK / 128), dim3(256), 0, stream>>>(
      Hb, (u16*)(ws + OFF_WFC1), fc1b, (u16*)(ws + OFF_U), nullptr, nullptr, nullptr,
      NTOK, 4096, 1024);
  gemm_bt<EPI_RESID><<<dim3(1024 / 128, NTOK / 128), dim3(256), 0, stream>>>(
      (u16*)(ws + OFF_U), (u16*)(ws + OFF_WFC2), fc2b, nullptr, out, out, g_mlp,
      NTOK, 1024, 4096);
}

// Round 2
// 468.406 us; speedup vs baseline: 1.1988x; 1.1988x over previous
//
#include <hip/hip_runtime.h>
#include <math.h>

typedef __attribute__((ext_vector_type(8))) short short8;
typedef __attribute__((ext_vector_type(4))) float f32x4;
typedef __attribute__((ext_vector_type(16))) float f32x16;
typedef unsigned short u16;
typedef unsigned int u32;
typedef __attribute__((ext_vector_type(4))) u32 u32x4;
typedef unsigned long long u64;

static constexpr int E = 1024, H = 16, LQ = 1024, LC = 512, Bn = 4, FF = 4096;
static constexpr int NTOK = Bn * LQ;   // 4096
static constexpr int NCTX = Bn * LC;   // 2048

// Q pre-scale: 1/sqrt(64) * log2(e)  (softmax runs in exp2 domain)
#define QSCALE 0.1803368801111244f
#define DEFER_THR 11.5f

// ---------------- workspace layout (bytes) ----------------
static constexpr size_t OFF_TCOS   = 0;                                    // 1024*32 f32
static constexpr size_t OFF_TSIN   = OFF_TCOS + (size_t)LQ*32*4;
static constexpr size_t OFF_BSAQKV = OFF_TSIN + (size_t)LQ*32*4;           // 3072 f32
static constexpr size_t OFF_BCAKV  = OFF_BSAQKV + 16384;                   // 2048 f32
static constexpr size_t OFF_WSAQKV = OFF_BCAKV + 16384;                    // [3072][1024] bf16
static constexpr size_t OFF_WSAP   = OFF_WSAQKV + (size_t)3072*1024*2;     // [1024][1024]
static constexpr size_t OFF_WCAQ   = OFF_WSAP   + (size_t)1024*1024*2;
static constexpr size_t OFF_WCAKV  = OFF_WCAQ   + (size_t)1024*1024*2;     // [2048][1024]
static constexpr size_t OFF_WCAP   = OFF_WCAKV  + (size_t)2048*1024*2;
static constexpr size_t OFF_WFC1   = OFF_WCAP   + (size_t)1024*1024*2;     // [4096][1024]
static constexpr size_t OFF_WFC2   = OFF_WFC1   + (size_t)4096*1024*2;     // [1024][4096]
static constexpr size_t OFF_CTXB   = OFF_WFC2   + (size_t)1024*4096*2;     // [2048][1024] bf16
static constexpr size_t OFF_H      = OFF_CTXB   + (size_t)2048*1024*2;     // [4096][1024] bf16 (LN out)
static constexpr size_t OFF_QKV    = OFF_H      + (size_t)4096*1024*2;     // [4096][3072] bf16
static constexpr size_t OFF_CAQ    = OFF_QKV;                              // [4096][1024]
static constexpr size_t OFF_CAKV   = OFF_QKV + (size_t)4096*1024*2;        // [2048][2048]
static constexpr size_t OFF_QR     = OFF_QKV + (size_t)4096*3072*2;        // [B,H,LQ,64]
static constexpr size_t OFF_KR     = OFF_QR  + (size_t)4096*1024*2;        // [B,H,Lk,64]
static constexpr size_t OFF_VT     = OFF_KR  + (size_t)4096*1024*2;        // [B,H,64,Lk]
static constexpr size_t OFF_AO     = OFF_VT  + (size_t)4096*1024*2;        // [4096][1024] bf16
static constexpr size_t OFF_U      = OFF_QKV;                              // fc1 out [4096][4096] bf16 reuses QKV+QR
static constexpr size_t WS_NEED    = OFF_AO + (size_t)4096*1024*2;         // ~105 MB

// ---------------- helpers ----------------
static __device__ __forceinline__ float bf2f(u16 u) {
  union { u32 i; float f; } un; un.i = ((u32)u) << 16; return un.f;
}
static __device__ __forceinline__ u16 f2bf(float f) {  // RNE
  union { float f; u32 u; } un; un.f = f;
  u32 u = un.u;
  return (u16)((u + 0x7FFFu + ((u >> 16) & 1u)) >> 16);
}
static __device__ __forceinline__ u64 pack4(u16 a, u16 b, u16 c, u16 d) {
  return (u64)a | ((u64)b << 16) | ((u64)c << 32) | ((u64)d << 48);
}
static __device__ __forceinline__ f32x4 mfma16(short8 a, short8 b, f32x4 c) {
  return __builtin_amdgcn_mfma_f32_16x16x32_bf16(a, b, c, 0, 0, 0);
}
static __device__ __forceinline__ f32x16 mfma32(short8 a, short8 b, f32x16 c) {
  return __builtin_amdgcn_mfma_f32_32x32x16_bf16(a, b, c, 0, 0, 0);
}
static __device__ __forceinline__ void gload_lds16(void* lds, const void* g) {
  __builtin_amdgcn_global_load_lds(
      (const __attribute__((address_space(1))) void*)g,
      (__attribute__((address_space(3))) void*)lds, 16, 0, 0);
}
static __device__ __forceinline__ float gelu_tanh(float x) {
  float t = tanhf(0.7978845608028654f * (x + 0.044715f * x * x * x));
  return 0.5f * x * (1.0f + t);
}
static __device__ __forceinline__ u32 cvtpk_bf16(float lo, float hi) {
  u32 r;
  asm("v_cvt_pk_bf16_f32 %0, %1, %2" : "=v"(r) : "v"(lo), "v"(hi));
  return r;
}

// ---------------- small kernels ----------------
__global__ __launch_bounds__(256) void build_tab(float* __restrict__ ct, float* __restrict__ st) {
  int idx = blockIdx.x * 256 + threadIdx.x;           // 1024*32 entries
  int pos = idx >> 5, i = idx & 31;
  float inv = powf(10000.f, -(float)i * (1.f / 32.f));
  float a = (float)pos * inv;
  ct[idx] = cosf(a);
  st[idx] = sinf(a);
}

__global__ __launch_bounds__(256) void cvt_bf16(const float* __restrict__ src, u16* __restrict__ dst, int n) {
  int i = (blockIdx.x * 256 + threadIdx.x) * 4;
  if (i + 3 < n) {
    float4 v = *(const float4*)(src + i);
    *(u64*)(dst + i) = pack4(f2bf(v.x), f2bf(v.y), f2bf(v.z), f2bf(v.w));
  }
}

__global__ __launch_bounds__(256) void copy_f32(const float* __restrict__ src, float* __restrict__ dst, int n) {
  int i = blockIdx.x * 256 + threadIdx.x;
  if (i < n) dst[i] = src[i];
}

// LN over last dim 1024, one row per block (256 threads, 4 f32 each), bf16 out.
__global__ __launch_bounds__(256) void ln_bf16(const float* __restrict__ x, const float* __restrict__ w,
                                               const float* __restrict__ b, u16* __restrict__ out) {
  __shared__ float red[4];
  int row = blockIdx.x, tid = threadIdx.x;
  const float* xr = x + (size_t)row * 1024;
  float4 v = ((const float4*)xr)[tid];
  float s = v.x + v.y + v.z + v.w;
#pragma unroll
  for (int off = 32; off; off >>= 1) s += __shfl_xor(s, off);
  if ((tid & 63) == 0) red[tid >> 6] = s;
  __syncthreads();
  float mean = (red[0] + red[1] + red[2] + red[3]) * (1.f / 1024.f);
  float dx = v.x - mean, dy = v.y - mean, dz = v.z - mean, dw = v.w - mean;
  float sq = dx * dx + dy * dy + dz * dz + dw * dw;
#pragma unroll
  for (int off = 32; off; off >>= 1) sq += __shfl_xor(sq, off);
  __syncthreads();
  if ((tid & 63) == 0) red[tid >> 6] = sq;
  __syncthreads();
  float var = (red[0] + red[1] + red[2] + red[3]) * (1.f / 1024.f);
  float rstd = rsqrtf(var + 1e-6f);
  float4 wv = ((const float4*)w)[tid];
  float4 bv = ((const float4*)b)[tid];
  u64 o = pack4(f2bf(dx * rstd * wv.x + bv.x), f2bf(dy * rstd * wv.y + bv.y),
                f2bf(dz * rstd * wv.z + bv.z), f2bf(dw * rstd * wv.w + bv.w));
  *(u64*)(out + (size_t)row * 1024 + tid * 4) = o;
}

// RoPE + layout scatter. src [T][ld] bf16 (+col0), 128 threads x 8 elems per token.
// ROPE=1: rotate pairs (×scale), dst [B,H,Lper,64]. TRANS=1: dst [B,H,64,Lper] (V^T).
template <int ROPE, int TRANS>
__global__ __launch_bounds__(128) void rope_scatter(const u16* __restrict__ src, int ld, int col0,
                                                    u16* __restrict__ dst,
                                                    const float* __restrict__ cosT,
                                                    const float* __restrict__ sinT, int Lper,
                                                    float scale) {
  int t = blockIdx.x;
  int b = t / Lper, l = t - b * Lper;
  int tid = threadIdx.x;
  int e0 = tid * 8;
  int h = e0 >> 6, d0 = e0 & 63;
  short8 vv = *(const short8*)(src + (size_t)t * ld + col0 + e0);
  if (ROPE) {
    short8 ov;
#pragma unroll
    for (int j = 0; j < 4; ++j) {
      float x1 = bf2f((u16)vv[2 * j]);
      float x2 = bf2f((u16)vv[2 * j + 1]);
      int i = (d0 >> 1) + j;
      float c = cosT[l * 32 + i], s = sinT[l * 32 + i];
      ov[2 * j]     = (short)f2bf((x1 * c - x2 * s) * scale);
      ov[2 * j + 1] = (short)f2bf((x1 * s + x2 * c) * scale);
    }
    *(short8*)(dst + (((size_t)b * H + h) * Lper + l) * 64 + d0) = ov;
  } else if (TRANS) {
#pragma unroll
    for (int m = 0; m < 8; ++m)
      dst[(((size_t)b * H + h) * 64 + d0 + m) * Lper + l] = (u16)vv[m];
  }
}

// ---------------- GEMM: C[M,N] = A[M,K] @ W[N,K]^T + bias, bf16 in / f32 acc ----------------
enum { EPI_BF16 = 0, EPI_GELU = 1, EPI_RESID = 2 };

template <int EPI>
__global__ __launch_bounds__(256, 2) void gemm_bt(const u16* __restrict__ A, const u16* __restrict__ W,
                                                  const float* __restrict__ bias, u16* outb, float* outf,
                                                  const float* res, const float* __restrict__ gate,
                                                  int M, int N, int K) {
  __shared__ u16 As[128 * 64];
  __shared__ u16 Bs[128 * 64];

  // bijective XCD swizzle (all our grids have nwg % 8 == 0)
  int nwg = gridDim.x * gridDim.y;
  int bid = blockIdx.y * gridDim.x + blockIdx.x;
  int cpx = nwg >> 3;
  int swz = (bid & 7) * cpx + (bid >> 3);
  int bx = swz % gridDim.x;
  int by = swz / gridDim.x;
  int row0 = by * 128, col0 = bx * 128;

  int tid = threadIdx.x;
  int lane = tid & 63, wid = tid >> 6;
  int wr = wid >> 1, wc = wid & 1;  // 2x2 waves, each owns 64x64
  int lr = lane & 15, lg = lane >> 4;

  f32x4 acc[4][4] = {};

  const int nkt = K >> 6;
  for (int kt = 0; kt < nkt; ++kt) {
    int k0 = kt << 6;
#pragma unroll
    for (int j = 0; j < 4; ++j) {
      int q = j * 256 + tid;           // chunk id 0..1023 (16B chunks)
      int r = q >> 3, p = q & 7;
      int sp = p ^ (r & 7);
      gload_lds16(As + (size_t)(j * 256 + wid * 64) * 8, A + (size_t)(row0 + r) * K + k0 + sp * 8);
      gload_lds16(Bs + (size_t)(j * 256 + wid * 64) * 8, W + (size_t)(col0 + r) * K + k0 + sp * 8);
    }
    __syncthreads();
#pragma unroll
    for (int kk = 0; kk < 2; ++kk) {
      short8 af[4], bf[4];
#pragma unroll
      for (int m = 0; m < 4; ++m) {
        int r = wr * 64 + m * 16 + lr;
        int sc = (kk * 4 + lg) ^ (r & 7);
        af[m] = *(const short8*)(As + r * 64 + sc * 8);
      }
#pragma unroll
      for (int n = 0; n < 4; ++n) {
        int r = wc * 64 + n * 16 + lr;
        int sc = (kk * 4 + lg) ^ (r & 7);
        bf[n] = *(const short8*)(Bs + r * 64 + sc * 8);
      }
#pragma unroll
      for (int m = 0; m < 4; ++m)
#pragma unroll
        for (int n = 0; n < 4; ++n)
          acc[m][n] = mfma16(af[m], bf[n], acc[m][n]);
    }
    __syncthreads();
  }

  // epilogue: C layout col=lane&15, row=(lane>>4)*4+i
#pragma unroll
  for (int n = 0; n < 4; ++n) {
    int cg = col0 + wc * 64 + n * 16 + lr;
    float bv = bias[cg];
#pragma unroll
    for (int m = 0; m < 4; ++m) {
#pragma unroll
      for (int i = 0; i < 4; ++i) {
        int rg = row0 + wr * 64 + m * 16 + lg * 4 + i;
        float v = acc[m][n][i] + bv;
        if (EPI == EPI_BF16) {
          outb[(size_t)rg * N + cg] = f2bf(v);
        } else if (EPI == EPI_GELU) {
          outb[(size_t)rg * N + cg] = f2bf(gelu_tanh(v));
        } else {
          float r = res[(size_t)rg * N + cg];
          outf[(size_t)rg * N + cg] = r + gate[cg] * v;
        }
      }
    }
  }
}

// ---------------- flash attention, swapped-QK^T 32x32 structure ----------------
// Q [BH,Lq,64] (pre-scaled by 1/8*log2e), K [BH,Lk,64], Vt [BH,64,Lk]; O [B,Lq,E] bf16.
// One wave per 32 Q-rows; KV tiles of 64; softmax in-register (exp2 domain).
template <int MASKED>
static __device__ __forceinline__ void attn_tile(const u16* Kb, const u16* Vb, const short8* qf,
                                                 int kb, int Lk, int q0, int l31, int hi,
                                                 float& m, float& lsum, f32x16& o0, f32x16& o1) {
  f32x16 s0 = {}, s1 = {};
#pragma unroll
  for (int s = 0; s < 4; ++s) {
    short8 kf0 = *(const short8*)(Kb + (size_t)(kb + l31) * 64 + s * 16 + hi * 8);
    short8 kf1 = *(const short8*)(Kb + (size_t)(kb + 32 + l31) * 64 + s * 16 + hi * 8);
    s0 = mfma32(kf0, qf[s], s0);   // S^T[k][q]
    s1 = mfma32(kf1, qf[s], s1);
  }
  if (MASKED) {
    int qg = q0 + l31;
#pragma unroll
    for (int r = 0; r < 16; ++r) {
      int kk = kb + (r & 3) + 8 * (r >> 2) + 4 * hi;
      if (kk > qg) s0[r] = -INFINITY;
      if (kk + 32 > qg) s1[r] = -INFINITY;
    }
  }
  // column (= q-row) max: 31 in-register + 1 cross-half shuffle
  float pm = -INFINITY;
#pragma unroll
  for (int r = 0; r < 16; ++r) pm = fmaxf(pm, fmaxf(s0[r], s1[r]));
  pm = fmaxf(pm, __shfl_xor(pm, 32));
  // defer-max rescale (T13)
  if (!__all(pm <= m + DEFER_THR)) {
    float mn = fmaxf(m, pm);
    float al = exp2f(m - mn);
    m = mn;
    lsum *= al;
#pragma unroll
    for (int r = 0; r < 16; ++r) {
      float alr = __shfl(al, (r & 3) + 8 * (r >> 2) + 4 * hi);
      o0[r] *= alr;
      o1[r] *= alr;
    }
  }
  float ts = 0.f;
#pragma unroll
  for (int r = 0; r < 16; ++r) {
    float p0 = exp2f(s0[r] - m);
    float p1 = exp2f(s1[r] - m);
    s0[r] = p0; s1[r] = p1;
    ts += p0 + p1;
  }
  ts += __shfl_xor(ts, 32);
  lsum += ts;
  // pack P (lane-local column) into PV A-fragments: cvt_pk + half-swap
  auto pack8 = [&](float a0, float a1, float a2, float a3,
                   float a4, float a5, float a6, float a7) -> short8 {
    u32 c0 = cvtpk_bf16(a0, a1), c1 = cvtpk_bf16(a2, a3);
    u32 c2 = cvtpk_bf16(a4, a5), c3 = cvtpk_bf16(a6, a7);
    u32 sw0 = (u32)__shfl_xor((int)c0, 32);
    u32 sw1 = (u32)__shfl_xor((int)c1, 32);
    u32 sw2 = (u32)__shfl_xor((int)c2, 32);
    u32 sw3 = (u32)__shfl_xor((int)c3, 32);
    u32x4 w;
    w[0] = hi ? sw2 : c0;
    w[1] = hi ? sw3 : c1;
    w[2] = hi ? c2 : sw0;
    w[3] = hi ? c3 : sw1;
    return __builtin_bit_cast(short8, w);
  };
  short8 pa0 = pack8(s0[0], s0[1], s0[2], s0[3], s0[4], s0[5], s0[6], s0[7]);
  short8 pa1 = pack8(s0[8], s0[9], s0[10], s0[11], s0[12], s0[13], s0[14], s0[15]);
  short8 pa2 = pack8(s1[0], s1[1], s1[2], s1[3], s1[4], s1[5], s1[6], s1[7]);
  short8 pa3 = pack8(s1[8], s1[9], s1[10], s1[11], s1[12], s1[13], s1[14], s1[15]);
  short8 pa[4] = {pa0, pa1, pa2, pa3};
#pragma unroll
  for (int ks = 0; ks < 4; ++ks) {
    short8 bv0 = *(const short8*)(Vb + (size_t)l31 * Lk + kb + ks * 16 + hi * 8);
    short8 bv1 = *(const short8*)(Vb + (size_t)(32 + l31) * Lk + kb + ks * 16 + hi * 8);
    o0 = mfma32(pa[ks], bv0, o0);
    o1 = mfma32(pa[ks], bv1, o1);
  }
}

template <int CAUSAL>
__global__ __launch_bounds__(256) void flash_attn2(const u16* __restrict__ Q, const u16* __restrict__ K,
                                                   const u16* __restrict__ Vt, u16* __restrict__ O,
                                                   int Lq, int Lk) {
  const int wid = threadIdx.x >> 6, lane = threadIdx.x & 63;
  const int l31 = lane & 31, hi = lane >> 5;
  int wg = blockIdx.x * 4 + wid;     // 4 independent waves per block, no barriers
  int bh = wg & 63;
  int qc = wg >> 6;
  if (CAUSAL) qc = (Lq >> 5) - 1 - qc;   // heavy q-chunks dispatch first
  int q0 = qc << 5;

  const u16* Qb = Q + ((size_t)bh * Lq + q0) * 64;
  const u16* Kb = K + (size_t)bh * Lk * 64;
  const u16* Vb = Vt + (size_t)bh * 64 * Lk;

  short8 qf[4];
#pragma unroll
  for (int s = 0; s < 4; ++s) qf[s] = *(const short8*)(Qb + (size_t)l31 * 64 + s * 16 + hi * 8);

  f32x16 o0 = {}, o1 = {};
  float m = -INFINITY, lsum = 0.f;

  int nt = CAUSAL ? ((q0 >> 6) + 1) : (Lk >> 6);
  for (int t = 0; t < nt - 1; ++t)
    attn_tile<0>(Kb, Vb, qf, t * 64, Lk, q0, l31, hi, m, lsum, o0, o1);
  if (CAUSAL)
    attn_tile<1>(Kb, Vb, qf, (nt - 1) * 64, Lk, q0, l31, hi, m, lsum, o0, o1);
  else
    attn_tile<0>(Kb, Vb, qf, (nt - 1) * 64, Lk, q0, l31, hi, m, lsum, o0, o1);

  float myinv = 1.f / lsum;
  int b = bh >> 4, h = bh & 15;
#pragma unroll
  for (int r = 0; r < 16; ++r) {
    int cr = (r & 3) + 8 * (r >> 2) + 4 * hi;
    float li = __shfl(myinv, cr);
    u16* op = O + ((size_t)b * Lq + q0 + cr) * 1024 + h * 64;
    op[l31] = f2bf(o0[r] * li);
    op[32 + l31] = f2bf(o1[r] * li);
  }
}

// ---------------- launch ----------------
extern "C" void kernel_launch(void* const* d_in, const int* in_sizes, int n_in,
                              void* d_out, int out_size, void* d_ws, size_t ws_size,
                              hipStream_t stream) {
  (void)in_sizes; (void)n_in; (void)out_size;
  if (ws_size < WS_NEED) return;  // need ~105 MB scratch

  const float* x     = (const float*)d_in[0];
  const float* ctx   = (const float*)d_in[1];
  const float* g_msa = (const float*)d_in[3];
  const float* g_ca  = (const float*)d_in[4];
  const float* g_mlp = (const float*)d_in[5];
  const float* n1w = (const float*)d_in[6],  *n1b = (const float*)d_in[7];
  const float* n2w = (const float*)d_in[8],  *n2b = (const float*)d_in[9];
  const float* n3w = (const float*)d_in[10], *n3b = (const float*)d_in[11];
  const float* sa_qw = (const float*)d_in[12], *sa_kw = (const float*)d_in[14];
  const float* sa_vw = (const float*)d_in[16], *sa_pw = (const float*)d_in[18];
  const float* sa_qb = (const float*)d_in[13], *sa_kb = (const float*)d_in[15];
  const float* sa_vb = (const float*)d_in[17], *sa_pb = (const float*)d_in[19];
  const float* ca_qw = (const float*)d_in[20], *ca_qb = (const float*)d_in[21];
  const float* ca_kw = (const float*)d_in[22], *ca_kb = (const float*)d_in[23];
  const float* ca_vw = (const float*)d_in[24], *ca_vb = (const float*)d_in[25];
  const float* ca_pw = (const float*)d_in[26], *ca_pb = (const float*)d_in[27];
  const float* fc1w = (const float*)d_in[28], *fc1b = (const float*)d_in[29];
  const float* fc2w = (const float*)d_in[30], *fc2b = (const float*)d_in[31];

  char* ws = (char*)d_ws;
  float* out = (float*)d_out;
  float* tcos = (float*)(ws + OFF_TCOS);
  float* tsin = (float*)(ws + OFF_TSIN);
  u16* Hb   = (u16*)(ws + OFF_H);
  u16* QKV  = (u16*)(ws + OFF_QKV);
  u16* QR   = (u16*)(ws + OFF_QR);
  u16* KR   = (u16*)(ws + OFF_KR);
  u16* VT   = (u16*)(ws + OFF_VT);
  u16* AO   = (u16*)(ws + OFF_AO);

  // RoPE tables
  build_tab<<<dim3(128), dim3(256), 0, stream>>>(tcos, tsin);

  // weight/context conversion (fp32 -> bf16), QKV / KV concat layouts
  auto cvt = [&](const float* s, size_t byte_off, int n) {
    cvt_bf16<<<dim3(n / 1024), dim3(256), 0, stream>>>(s, (u16*)(ws + byte_off), n);
  };
  cvt(sa_qw, OFF_WSAQKV, 1024 * 1024);
  cvt(sa_kw, OFF_WSAQKV + (size_t)1024 * 1024 * 2, 1024 * 1024);
  cvt(sa_vw, OFF_WSAQKV + (size_t)2048 * 1024 * 2, 1024 * 1024);
  cvt(sa_pw, OFF_WSAP, 1024 * 1024);
  cvt(ca_qw, OFF_WCAQ, 1024 * 1024);
  cvt(ca_kw, OFF_WCAKV, 1024 * 1024);
  cvt(ca_vw, OFF_WCAKV + (size_t)1024 * 1024 * 2, 1024 * 1024);
  cvt(ca_pw, OFF_WCAP, 1024 * 1024);
  cvt(fc1w, OFF_WFC1, 4096 * 1024);
  cvt(fc2w, OFF_WFC2, 1024 * 4096);
  cvt(ctx, OFF_CTXB, NCTX * 1024);
  copy_f32<<<dim3(4), dim3(256), 0, stream>>>(sa_qb, (float*)(ws + OFF_BSAQKV), 1024);
  copy_f32<<<dim3(4), dim3(256), 0, stream>>>(sa_kb, (float*)(ws + OFF_BSAQKV + 4096), 1024);
  copy_f32<<<dim3(4), dim3(256), 0, stream>>>(sa_vb, (float*)(ws + OFF_BSAQKV + 8192), 1024);
  copy_f32<<<dim3(4), dim3(256), 0, stream>>>(ca_kb, (float*)(ws + OFF_BCAKV), 1024);
  copy_f32<<<dim3(4), dim3(256), 0, stream>>>(ca_vb, (float*)(ws + OFF_BCAKV + 4096), 1024);

  // ---- self-attention ----
  ln_bf16<<<dim3(NTOK), dim3(256), 0, stream>>>(x, n1w, n1b, Hb);
  gemm_bt<EPI_BF16><<<dim3(3072 / 128, NTOK / 128), dim3(256), 0, stream>>>(
      Hb, (u16*)(ws + OFF_WSAQKV), (float*)(ws + OFF_BSAQKV), QKV, nullptr, nullptr, nullptr,
      NTOK, 3072, 1024);
  rope_scatter<1, 0><<<dim3(NTOK), dim3(128), 0, stream>>>(QKV, 3072, 0, QR, tcos, tsin, LQ, QSCALE);
  rope_scatter<1, 0><<<dim3(NTOK), dim3(128), 0, stream>>>(QKV, 3072, 1024, KR, tcos, tsin, LQ, 1.0f);
  rope_scatter<0, 1><<<dim3(NTOK), dim3(128), 0, stream>>>(QKV, 3072, 2048, VT, tcos, tsin, LQ, 1.0f);
  flash_attn2<1><<<dim3(512), dim3(256), 0, stream>>>(QR, KR, VT, AO, LQ, LQ);
  gemm_bt<EPI_RESID><<<dim3(1024 / 128, NTOK / 128), dim3(256), 0, stream>>>(
      AO, (u16*)(ws + OFF_WSAP), sa_pb, nullptr, out, x, g_msa, NTOK, 1024, 1024);

  // ---- cross-attention ----
  ln_bf16<<<dim3(NTOK), dim3(256), 0, stream>>>(out, n2w, n2b, Hb);
  gemm_bt<EPI_BF16><<<dim3(1024 / 128, NTOK / 128), dim3(256), 0, stream>>>(
      Hb, (u16*)(ws + OFF_WCAQ), ca_qb, (u16*)(ws + OFF_CAQ), nullptr, nullptr, nullptr,
      NTOK, 1024, 1024);
  gemm_bt<EPI_BF16><<<dim3(2048 / 128, NCTX / 128), dim3(256), 0, stream>>>(
      (u16*)(ws + OFF_CTXB), (u16*)(ws + OFF_WCAKV), (float*)(ws + OFF_BCAKV),
      (u16*)(ws + OFF_CAKV), nullptr, nullptr, nullptr, NCTX, 2048, 1024);
  rope_scatter<1, 0><<<dim3(NTOK), dim3(128), 0, stream>>>((u16*)(ws + OFF_CAQ), 1024, 0, QR, tcos, tsin, LQ, QSCALE);
  rope_scatter<1, 0><<<dim3(NCTX), dim3(128), 0, stream>>>((u16*)(ws + OFF_CAKV), 2048, 0, KR, tcos, tsin, LC, 1.0f);
  rope_scatter<0, 1><<<dim3(NCTX), dim3(128), 0, stream>>>((u16*)(ws + OFF_CAKV), 2048, 1024, VT, tcos, tsin, LC, 1.0f);
  flash_attn2<0><<<dim3(512), dim3(256), 0, stream>>>(QR, KR, VT, AO, LQ, LC);
  gemm_bt<EPI_RESID><<<dim3(1024 / 128, NTOK / 128), dim3(256), 0, stream>>>(
      AO, (u16*)(ws + OFF_WCAP), ca_pb, nullptr, out, out, g_ca, NTOK, 1024, 1024);

  // ---- MLP ----
  ln_bf16<<<dim3(NTOK), dim3(256), 0, stream>>>(out, n3w, n3b, Hb);
  gemm_bt<EPI_GELU><<<dim3(4096 / 128, NTOK / 128), dim3(256), 0, stream>>>(
      Hb, (u16*)(ws + OFF_WFC1), fc1b, (u16*)(ws + OFF_U), nullptr, nullptr, nullptr,
      NTOK, 4096, 1024);
  gemm_bt<EPI_RESID><<<dim3(1024 / 128, NTOK / 128), dim3(256), 0, stream>>>(
      (u16*)(ws + OFF_U), (u16*)(ws + OFF_WFC2), fc2b, nullptr, out, out, g_mlp,
      NTOK, 1024, 4096);
}

// Round 3
// 423.663 us; speedup vs baseline: 1.3254x; 1.1056x over previous
//
#include <hip/hip_runtime.h>
#include <math.h>

typedef __attribute__((ext_vector_type(8))) short short8;
typedef __attribute__((ext_vector_type(4))) float f32x4;
typedef __attribute__((ext_vector_type(16))) float f32x16;
typedef unsigned short u16;
typedef unsigned int u32;
typedef __attribute__((ext_vector_type(2))) u32 u32x2;
typedef __attribute__((ext_vector_type(4))) u32 u32x4;
typedef unsigned long long u64;

static constexpr int E = 1024, H = 16, LQ = 1024, LC = 512, Bn = 4, FF = 4096;
static constexpr int NTOK = Bn * LQ;   // 4096
static constexpr int NCTX = Bn * LC;   // 2048

// Q pre-scale: 1/sqrt(64) * log2(e)  (softmax runs in exp2 domain)
#define QSCALE 0.1803368801111244f
#define DEFER_THR 11.5f

// ---------------- workspace layout (bytes) ----------------
static constexpr size_t OFF_TCOS   = 0;                                    // 1024*32 f32
static constexpr size_t OFF_TSIN   = OFF_TCOS + (size_t)LQ*32*4;
static constexpr size_t OFF_BSAQKV = OFF_TSIN + (size_t)LQ*32*4;           // 3072 f32 (+ca_k/v bias after)
static constexpr size_t OFF_BCAKV  = OFF_BSAQKV + 16384;                   // 2048 f32
// contiguous bf16 weight region (order matters for cvt_all):
static constexpr size_t OFF_WSAQKV = OFF_BCAKV + 16384;                    // [3072][1024] bf16
static constexpr size_t OFF_WSAP   = OFF_WSAQKV + (size_t)3072*1024*2;     // [1024][1024]
static constexpr size_t OFF_WCAQ   = OFF_WSAP   + (size_t)1024*1024*2;
static constexpr size_t OFF_WCAKV  = OFF_WCAQ   + (size_t)1024*1024*2;     // [2048][1024]
static constexpr size_t OFF_WCAP   = OFF_WCAKV  + (size_t)2048*1024*2;
static constexpr size_t OFF_WFC1   = OFF_WCAP   + (size_t)1024*1024*2;     // [4096][1024]
static constexpr size_t OFF_WFC2   = OFF_WFC1   + (size_t)4096*1024*2;     // [1024][4096]
static constexpr size_t OFF_CTXB   = OFF_WFC2   + (size_t)1024*4096*2;     // [2048][1024] bf16
static constexpr size_t OFF_H      = OFF_CTXB   + (size_t)2048*1024*2;     // [4096][1024] bf16 (LN out)
static constexpr size_t OFF_QKV    = OFF_H      + (size_t)4096*1024*2;     // [4096][3072] bf16
static constexpr size_t OFF_CAQ    = OFF_QKV;                              // [4096][1024]
static constexpr size_t OFF_CAKV   = OFF_QKV + (size_t)4096*1024*2;        // [2048][2048]
static constexpr size_t OFF_QR     = OFF_QKV + (size_t)4096*3072*2;        // [B,H,LQ,64]
static constexpr size_t OFF_KR     = OFF_QR  + (size_t)4096*1024*2;        // [B,H,Lk,64]
static constexpr size_t OFF_VT     = OFF_KR  + (size_t)4096*1024*2;        // [B,H,64,Lk]
static constexpr size_t OFF_AO     = OFF_VT  + (size_t)4096*1024*2;        // [4096][1024] bf16
static constexpr size_t OFF_U      = OFF_QKV;                              // fc1 out [4096][4096] bf16 reuses QKV+QR
static constexpr size_t WS_NEED    = OFF_AO + (size_t)4096*1024*2;         // ~105 MB

// ---------------- helpers ----------------
static __device__ __forceinline__ float bf2f(u16 u) {
  union { u32 i; float f; } un; un.i = ((u32)u) << 16; return un.f;
}
static __device__ __forceinline__ u16 f2bf(float f) {  // RNE
  union { float f; u32 u; } un; un.f = f;
  u32 u = un.u;
  return (u16)((u + 0x7FFFu + ((u >> 16) & 1u)) >> 16);
}
static __device__ __forceinline__ u64 pack4(u16 a, u16 b, u16 c, u16 d) {
  return (u64)a | ((u64)b << 16) | ((u64)c << 32) | ((u64)d << 48);
}
static __device__ __forceinline__ f32x4 mfma16(short8 a, short8 b, f32x4 c) {
  return __builtin_amdgcn_mfma_f32_16x16x32_bf16(a, b, c, 0, 0, 0);
}
static __device__ __forceinline__ f32x16 mfma32(short8 a, short8 b, f32x16 c) {
  return __builtin_amdgcn_mfma_f32_32x32x16_bf16(a, b, c, 0, 0, 0);
}
static __device__ __forceinline__ void gload_lds16(void* lds, const void* g) {
  __builtin_amdgcn_global_load_lds(
      (const __attribute__((address_space(1))) void*)g,
      (__attribute__((address_space(3))) void*)lds, 16, 0, 0);
}
static __device__ __forceinline__ float gelu_tanh(float x) {
  float t = tanhf(0.7978845608028654f * (x + 0.044715f * x * x * x));
  return 0.5f * x * (1.0f + t);
}
static __device__ __forceinline__ u32 cvtpk_bf16(float lo, float hi) {
  u32 r;
  asm("v_cvt_pk_bf16_f32 %0, %1, %2" : "=v"(r) : "v"(lo), "v"(hi));
  return r;
}

// ---------------- small kernels ----------------
__global__ __launch_bounds__(256) void build_tab(float* __restrict__ ct, float* __restrict__ st) {
  int idx = blockIdx.x * 256 + threadIdx.x;           // 1024*32 entries
  int pos = idx >> 5, i = idx & 31;
  float inv = powf(10000.f, -(float)i * (1.f / 32.f));
  float a = (float)pos * inv;
  ct[idx] = cosf(a);
  st[idx] = sinf(a);
}

// fused fp32->bf16 conversion of all weights + context into the contiguous
// bf16 ws region. 11 segments, sizes (in 4-elem units): 8 x 262144, 2 x 1048576, 524288.
struct Cvt11 { const float* s[11]; };
__global__ __launch_bounds__(256) void cvt_all(Cvt11 a, u16* __restrict__ dst) {
  u32 gid = blockIdx.x * 256 + threadIdx.x;   // 0 .. 4718591
  u32 s, off;
  if (gid < 2097152u)      { s = gid >> 18;                        off = gid & 262143u; }
  else if (gid < 4194304u) { u32 t = gid - 2097152u; s = 8 + (t >> 20); off = t & 1048575u; }
  else                     { s = 10;                               off = gid - 4194304u; }
  float4 v = *(const float4*)(a.s[s] + (size_t)off * 4);
  *(u64*)(dst + (size_t)gid * 4) = pack4(f2bf(v.x), f2bf(v.y), f2bf(v.z), f2bf(v.w));
}

// fused bias copies: sa_q,sa_k,sa_v -> BSAQKV(+0,+1024,+2048); ca_k,ca_v -> BCAKV(+0,+1024)
// dst base = BSAQKV; BCAKV = BSAQKV + 4096 floats.
struct Cp5 { const float* s[5]; };
__global__ __launch_bounds__(256) void copy5(Cp5 a, float* __restrict__ dst) {
  int gid = blockIdx.x * 256 + threadIdx.x;   // 0..5119
  int s = gid >> 10, off = gid & 1023;
  int doff = (s < 3) ? s * 1024 : 4096 + (s - 3) * 1024;
  dst[doff + off] = a.s[s][off];
}

// out[row][c] += gate[c]*bias[c]  (init pass for split-K atomic GEMM)
__global__ __launch_bounds__(256) void init_bias_gate(float* __restrict__ out, const float* __restrict__ bias,
                                                      const float* __restrict__ gate) {
  int i = (blockIdx.x * 256 + threadIdx.x) * 4;
  int c = i & 1023;
  float4 o = *(float4*)(out + i);
  o.x += gate[c] * bias[c];
  o.y += gate[c + 1] * bias[c + 1];
  o.z += gate[c + 2] * bias[c + 2];
  o.w += gate[c + 3] * bias[c + 3];
  *(float4*)(out + i) = o;
}

// LN over last dim 1024, one row per block (256 threads, 4 f32 each), bf16 out.
__global__ __launch_bounds__(256) void ln_bf16(const float* __restrict__ x, const float* __restrict__ w,
                                               const float* __restrict__ b, u16* __restrict__ out) {
  __shared__ float red[4];
  int row = blockIdx.x, tid = threadIdx.x;
  const float* xr = x + (size_t)row * 1024;
  float4 v = ((const float4*)xr)[tid];
  float s = v.x + v.y + v.z + v.w;
#pragma unroll
  for (int off = 32; off; off >>= 1) s += __shfl_xor(s, off);
  if ((tid & 63) == 0) red[tid >> 6] = s;
  __syncthreads();
  float mean = (red[0] + red[1] + red[2] + red[3]) * (1.f / 1024.f);
  float dx = v.x - mean, dy = v.y - mean, dz = v.z - mean, dw = v.w - mean;
  float sq = dx * dx + dy * dy + dz * dz + dw * dw;
#pragma unroll
  for (int off = 32; off; off >>= 1) sq += __shfl_xor(sq, off);
  __syncthreads();
  if ((tid & 63) == 0) red[tid >> 6] = sq;
  __syncthreads();
  float var = (red[0] + red[1] + red[2] + red[3]) * (1.f / 1024.f);
  float rstd = rsqrtf(var + 1e-6f);
  float4 wv = ((const float4*)w)[tid];
  float4 bv = ((const float4*)b)[tid];
  u64 o = pack4(f2bf(dx * rstd * wv.x + bv.x), f2bf(dy * rstd * wv.y + bv.y),
                f2bf(dz * rstd * wv.z + bv.z), f2bf(dw * rstd * wv.w + bv.w));
  *(u64*)(out + (size_t)row * 1024 + tid * 4) = o;
}

// RoPE + layout scatter. src [T][ld] bf16 (+col0), 128 threads x 8 elems per token.
// ROPE=1: rotate pairs (×scale), dst [B,H,Lper,64]. TRANS=1: dst [B,H,64,Lper] (V^T).
template <int ROPE, int TRANS>
__global__ __launch_bounds__(128) void rope_scatter(const u16* __restrict__ src, int ld, int col0,
                                                    u16* __restrict__ dst,
                                                    const float* __restrict__ cosT,
                                                    const float* __restrict__ sinT, int Lper,
                                                    float scale) {
  int t = blockIdx.x;
  int b = t / Lper, l = t - b * Lper;
  int tid = threadIdx.x;
  int e0 = tid * 8;
  int h = e0 >> 6, d0 = e0 & 63;
  short8 vv = *(const short8*)(src + (size_t)t * ld + col0 + e0);
  if (ROPE) {
    short8 ov;
#pragma unroll
    for (int j = 0; j < 4; ++j) {
      float x1 = bf2f((u16)vv[2 * j]);
      float x2 = bf2f((u16)vv[2 * j + 1]);
      int i = (d0 >> 1) + j;
      float c = cosT[l * 32 + i], s = sinT[l * 32 + i];
      ov[2 * j]     = (short)f2bf((x1 * c - x2 * s) * scale);
      ov[2 * j + 1] = (short)f2bf((x1 * s + x2 * c) * scale);
    }
    *(short8*)(dst + (((size_t)b * H + h) * Lper + l) * 64 + d0) = ov;
  } else if (TRANS) {
#pragma unroll
    for (int m = 0; m < 8; ++m)
      dst[(((size_t)b * H + h) * 64 + d0 + m) * Lper + l] = (u16)vv[m];
  }
}

// ---------------- GEMM: C[M,N] = A[M,K] @ W[N,K]^T + bias ----------------
// 128x128 tile, BK=64, 512 threads (8 waves, 2x4), double-buffered LDS with
// 1-deep global_load_lds prefetch (T3-lite 2-phase).
enum { EPI_BF16 = 0, EPI_GELU = 1, EPI_RESID = 2, EPI_ATOMIC = 3 };

template <int EPI>
__global__ __launch_bounds__(512, 4) void gemm2(const u16* __restrict__ A, const u16* __restrict__ W,
                                                const float* __restrict__ bias, u16* outb, float* outf,
                                                const float* res, const float* __restrict__ gate,
                                                int M, int N, int K, int kchunks) {
  __shared__ u16 As[2][128 * 64];
  __shared__ u16 Bs[2][128 * 64];

  // bijective XCD swizzle over the x-y grid (all our x*y grids are %8==0)
  int nwg = gridDim.x * gridDim.y;
  int bid = blockIdx.y * gridDim.x + blockIdx.x;
  int cpx = nwg >> 3;
  int swz = (bid & 7) * cpx + (bid >> 3);
  int bx = swz % gridDim.x;
  int by = swz / gridDim.x;
  int row0 = by * 128, col0 = bx * 128;

  const int Kc = K / kchunks;
  const int kbase = blockIdx.z * Kc;

  int tid = threadIdx.x;
  int lane = tid & 63, wid = tid >> 6;
  int wr = wid >> 2, wc = wid & 3;  // 2x4 waves, each owns 64x32
  int lr = lane & 15, lg = lane >> 4;

  // per-thread staging addresses (2 x 16B chunks each for A and B per tile)
  size_t a_off0, a_off1, b_off0, b_off1;
  int l_off0 = tid * 8, l_off1 = (512 + tid) * 8;
  {
    int q = tid, r = q >> 3, p = q & 7, sp = p ^ (r & 7);
    a_off0 = (size_t)(row0 + r) * K + sp * 8;
    b_off0 = (size_t)(col0 + r) * K + sp * 8;
    q = 512 + tid; r = q >> 3; p = q & 7; sp = p ^ (r & 7);
    a_off1 = (size_t)(row0 + r) * K + sp * 8;
    b_off1 = (size_t)(col0 + r) * K + sp * 8;
  }

  f32x4 acc[4][2] = {};

  const int nkt = Kc >> 6;
  // prologue: stage tile 0
  {
    int k0 = kbase;
    gload_lds16(&As[0][l_off0], A + a_off0 + k0);
    gload_lds16(&Bs[0][l_off0], W + b_off0 + k0);
    gload_lds16(&As[0][l_off1], A + a_off1 + k0);
    gload_lds16(&Bs[0][l_off1], W + b_off1 + k0);
  }
  __syncthreads();

  for (int kt = 0; kt < nkt; ++kt) {
    int cur = kt & 1;
    if (kt + 1 < nkt) {  // prefetch next tile into the other buffer
      int k0 = kbase + ((kt + 1) << 6);
      gload_lds16(&As[cur ^ 1][l_off0], A + a_off0 + k0);
      gload_lds16(&Bs[cur ^ 1][l_off0], W + b_off0 + k0);
      gload_lds16(&As[cur ^ 1][l_off1], A + a_off1 + k0);
      gload_lds16(&Bs[cur ^ 1][l_off1], W + b_off1 + k0);
    }
#pragma unroll
    for (int kk = 0; kk < 2; ++kk) {
      short8 af[4], bfr[2];
#pragma unroll
      for (int m = 0; m < 4; ++m) {
        int r = wr * 64 + m * 16 + lr;
        int sc = (kk * 4 + lg) ^ (r & 7);
        af[m] = *(const short8*)(&As[cur][r * 64 + sc * 8]);
      }
#pragma unroll
      for (int n = 0; n < 2; ++n) {
        int r = wc * 32 + n * 16 + lr;
        int sc = (kk * 4 + lg) ^ (r & 7);
        bfr[n] = *(const short8*)(&Bs[cur][r * 64 + sc * 8]);
      }
#pragma unroll
      for (int m = 0; m < 4; ++m)
#pragma unroll
        for (int n = 0; n < 2; ++n)
          acc[m][n] = mfma16(af[m], bfr[n], acc[m][n]);
    }
    __syncthreads();  // drains vmcnt(0): prefetched tile ready; buffers safe to swap
  }

  // epilogue: C frag layout col=lane&15, row=(lane>>4)*4+i
#pragma unroll
  for (int n = 0; n < 2; ++n) {
    int cg = col0 + wc * 32 + n * 16 + lr;
    float bv = (EPI == EPI_ATOMIC) ? 0.f : bias[cg];
#pragma unroll
    for (int m = 0; m < 4; ++m) {
#pragma unroll
      for (int i = 0; i < 4; ++i) {
        int rg = row0 + wr * 64 + m * 16 + lg * 4 + i;
        float v = acc[m][n][i] + bv;
        if (EPI == EPI_BF16) {
          outb[(size_t)rg * N + cg] = f2bf(v);
        } else if (EPI == EPI_GELU) {
          outb[(size_t)rg * N + cg] = f2bf(gelu_tanh(v));
        } else if (EPI == EPI_RESID) {
          float r = res[(size_t)rg * N + cg];
          outf[(size_t)rg * N + cg] = r + gate[cg] * v;
        } else {  // EPI_ATOMIC: bias+gate pre-applied by init_bias_gate
          atomicAdd(&outf[(size_t)rg * N + cg], gate[cg] * v);
        }
      }
    }
  }
}

// ---------------- flash attention, swapped-QK^T 32x32 structure ----------------
// Q [BH,Lq,64] (pre-scaled by 1/8*log2e), K [BH,Lk,64], Vt [BH,64,Lk]; O [B,Lq,E] bf16.
// One wave per 32 Q-rows; KV tiles of 64; softmax in-register (exp2 domain).
// Kt = K + kb*64; Vp0/Vp1 = Vt rows l31 / 32+l31, advanced to column kb.
template <int MASKED>
static __device__ __forceinline__ void attn_tile(const u16* Kt, const u16* Vp0, const u16* Vp1,
                                                 const short8* qf, int kb, int q0, int l31, int hi,
                                                 float& m, float& lsum, f32x16& o0, f32x16& o1) {
  f32x16 s0 = {}, s1 = {};
  const u16* kp0 = Kt + (size_t)l31 * 64 + hi * 8;
  const u16* kp1 = Kt + (size_t)(32 + l31) * 64 + hi * 8;
  __builtin_amdgcn_s_setprio(1);
#pragma unroll
  for (int s = 0; s < 4; ++s) {
    short8 kf0 = *(const short8*)(kp0 + s * 16);
    short8 kf1 = *(const short8*)(kp1 + s * 16);
    s0 = mfma32(kf0, qf[s], s0);   // S^T[k][q]
    s1 = mfma32(kf1, qf[s], s1);
  }
  __builtin_amdgcn_s_setprio(0);
  if (MASKED) {
    int qg = q0 + l31;
#pragma unroll
    for (int r = 0; r < 16; ++r) {
      int kk = kb + (r & 3) + 8 * (r >> 2) + 4 * hi;
      if (kk > qg) s0[r] = -INFINITY;
      if (kk + 32 > qg) s1[r] = -INFINITY;
    }
  }
  // column (= q-row) max: 31 in-register + 1 cross-half shuffle
  float pm = -INFINITY;
#pragma unroll
  for (int r = 0; r < 16; ++r) pm = fmaxf(pm, fmaxf(s0[r], s1[r]));
  pm = fmaxf(pm, __shfl_xor(pm, 32));
  // defer-max rescale (T13)
  if (!__all(pm <= m + DEFER_THR)) {
    float mn = fmaxf(m, pm);
    float al = exp2f(m - mn);
    m = mn;
    lsum *= al;
#pragma unroll
    for (int r = 0; r < 16; ++r) {
      float alr = __shfl(al, (r & 3) + 8 * (r >> 2) + 4 * hi);
      o0[r] *= alr;
      o1[r] *= alr;
    }
  }
  float ts = 0.f;
#pragma unroll
  for (int r = 0; r < 16; ++r) {
    float p0 = exp2f(s0[r] - m);
    float p1 = exp2f(s1[r] - m);
    s0[r] = p0; s1[r] = p1;
    ts += p0 + p1;
  }
  ts += __shfl_xor(ts, 32);
  lsum += ts;
  // pack P (lane-local column) into PV A-fragments: cvt_pk + permlane32_swap (T12)
  auto pack8 = [&](float a0, float a1, float a2, float a3,
                   float a4, float a5, float a6, float a7) -> short8 {
    u32 c0 = cvtpk_bf16(a0, a1), c1 = cvtpk_bf16(a2, a3);
    u32 c2 = cvtpk_bf16(a4, a5), c3 = cvtpk_bf16(a6, a7);
    // swap(vdst.hi <-> vsrc.lo): r[0] = {c0.lo || c2.lo}, r[1] = {c0.hi || c2.hi}
    u32x2 r02 = __builtin_amdgcn_permlane32_swap(c0, c2, false, false);
    u32x2 r13 = __builtin_amdgcn_permlane32_swap(c1, c3, false, false);
    u32x4 w;
    w[0] = r02[0]; w[1] = r13[0]; w[2] = r02[1]; w[3] = r13[1];
    return __builtin_bit_cast(short8, w);
  };
  short8 pa0 = pack8(s0[0], s0[1], s0[2], s0[3], s0[4], s0[5], s0[6], s0[7]);
  short8 pa1 = pack8(s0[8], s0[9], s0[10], s0[11], s0[12], s0[13], s0[14], s0[15]);
  short8 pa2 = pack8(s1[0], s1[1], s1[2], s1[3], s1[4], s1[5], s1[6], s1[7]);
  short8 pa3 = pack8(s1[8], s1[9], s1[10], s1[11], s1[12], s1[13], s1[14], s1[15]);
  short8 pa[4] = {pa0, pa1, pa2, pa3};
  __builtin_amdgcn_s_setprio(1);
#pragma unroll
  for (int ks = 0; ks < 4; ++ks) {
    short8 bv0 = *(const short8*)(Vp0 + ks * 16 + hi * 8);
    short8 bv1 = *(const short8*)(Vp1 + ks * 16 + hi * 8);
    o0 = mfma32(pa[ks], bv0, o0);
    o1 = mfma32(pa[ks], bv1, o1);
  }
  __builtin_amdgcn_s_setprio(0);
}

template <int CAUSAL>
__global__ __launch_bounds__(256) void flash_attn2(const u16* __restrict__ Q, const u16* __restrict__ K,
                                                   const u16* __restrict__ Vt, u16* __restrict__ O,
                                                   int Lq, int Lk) {
  const int wid = threadIdx.x >> 6, lane = threadIdx.x & 63;
  const int l31 = lane & 31, hi = lane >> 5;
  int wg = blockIdx.x * 4 + wid;     // 4 independent waves per block, no barriers
  int bh = wg & 63;
  int qc = wg >> 6;
  if (CAUSAL) qc = (Lq >> 5) - 1 - qc;   // heavy q-chunks dispatch first
  int q0 = qc << 5;

  const u16* Qb = Q + ((size_t)bh * Lq + q0) * 64;
  const u16* Kb = K + (size_t)bh * Lk * 64;
  const u16* Vb = Vt + (size_t)bh * 64 * Lk;

  short8 qf[4];
#pragma unroll
  for (int s = 0; s < 4; ++s) qf[s] = *(const short8*)(Qb + (size_t)l31 * 64 + s * 16 + hi * 8);

  f32x16 o0 = {}, o1 = {};
  float m = -INFINITY, lsum = 0.f;

  const u16* Kt = Kb;
  const u16* Vp0 = Vb + (size_t)l31 * Lk;
  const u16* Vp1 = Vb + (size_t)(32 + l31) * Lk;

  int nt = CAUSAL ? ((q0 >> 6) + 1) : (Lk >> 6);
  for (int t = 0; t < nt - 1; ++t) {
    attn_tile<0>(Kt, Vp0, Vp1, qf, t * 64, q0, l31, hi, m, lsum, o0, o1);
    Kt += 64 * 64; Vp0 += 64; Vp1 += 64;
  }
  if (CAUSAL)
    attn_tile<1>(Kt, Vp0, Vp1, qf, (nt - 1) * 64, q0, l31, hi, m, lsum, o0, o1);
  else
    attn_tile<0>(Kt, Vp0, Vp1, qf, (nt - 1) * 64, q0, l31, hi, m, lsum, o0, o1);

  float myinv = 1.f / lsum;
  int b = bh >> 4, h = bh & 15;
#pragma unroll
  for (int r = 0; r < 16; ++r) {
    int cr = (r & 3) + 8 * (r >> 2) + 4 * hi;
    float li = __shfl(myinv, cr);
    u16* op = O + ((size_t)b * Lq + q0 + cr) * 1024 + h * 64;
    op[l31] = f2bf(o0[r] * li);
    op[32 + l31] = f2bf(o1[r] * li);
  }
}

// ---------------- launch ----------------
extern "C" void kernel_launch(void* const* d_in, const int* in_sizes, int n_in,
                              void* d_out, int out_size, void* d_ws, size_t ws_size,
                              hipStream_t stream) {
  (void)in_sizes; (void)n_in; (void)out_size;
  if (ws_size < WS_NEED) return;  // need ~105 MB scratch

  const float* x     = (const float*)d_in[0];
  const float* ctx   = (const float*)d_in[1];
  const float* g_msa = (const float*)d_in[3];
  const float* g_ca  = (const float*)d_in[4];
  const float* g_mlp = (const float*)d_in[5];
  const float* n1w = (const float*)d_in[6],  *n1b = (const float*)d_in[7];
  const float* n2w = (const float*)d_in[8],  *n2b = (const float*)d_in[9];
  const float* n3w = (const float*)d_in[10], *n3b = (const float*)d_in[11];
  const float* sa_qw = (const float*)d_in[12], *sa_kw = (const float*)d_in[14];
  const float* sa_vw = (const float*)d_in[16], *sa_pw = (const float*)d_in[18];
  const float* sa_qb = (const float*)d_in[13], *sa_kb = (const float*)d_in[15];
  const float* sa_vb = (const float*)d_in[17], *sa_pb = (const float*)d_in[19];
  const float* ca_qw = (const float*)d_in[20], *ca_qb = (const float*)d_in[21];
  const float* ca_kw = (const float*)d_in[22], *ca_kb = (const float*)d_in[23];
  const float* ca_vw = (const float*)d_in[24], *ca_vb = (const float*)d_in[25];
  const float* ca_pw = (const float*)d_in[26], *ca_pb = (const float*)d_in[27];
  const float* fc1w = (const float*)d_in[28], *fc1b = (const float*)d_in[29];
  const float* fc2w = (const float*)d_in[30], *fc2b = (const float*)d_in[31];

  char* ws = (char*)d_ws;
  float* out = (float*)d_out;
  float* tcos = (float*)(ws + OFF_TCOS);
  float* tsin = (float*)(ws + OFF_TSIN);
  u16* Hb   = (u16*)(ws + OFF_H);
  u16* QKV  = (u16*)(ws + OFF_QKV);
  u16* QR   = (u16*)(ws + OFF_QR);
  u16* KR   = (u16*)(ws + OFF_KR);
  u16* VT   = (u16*)(ws + OFF_VT);
  u16* AO   = (u16*)(ws + OFF_AO);

  // RoPE tables
  build_tab<<<dim3(128), dim3(256), 0, stream>>>(tcos, tsin);

  // fused weight/context conversion (fp32 -> bf16) into contiguous ws region
  Cvt11 ca;
  ca.s[0] = sa_qw; ca.s[1] = sa_kw; ca.s[2] = sa_vw; ca.s[3] = sa_pw;
  ca.s[4] = ca_qw; ca.s[5] = ca_kw; ca.s[6] = ca_vw; ca.s[7] = ca_pw;
  ca.s[8] = fc1w;  ca.s[9] = fc2w;  ca.s[10] = ctx;
  cvt_all<<<dim3(18432), dim3(256), 0, stream>>>(ca, (u16*)(ws + OFF_WSAQKV));
  Cp5 cp;
  cp.s[0] = sa_qb; cp.s[1] = sa_kb; cp.s[2] = sa_vb; cp.s[3] = ca_kb; cp.s[4] = ca_vb;
  copy5<<<dim3(20), dim3(256), 0, stream>>>(cp, (float*)(ws + OFF_BSAQKV));

  // ---- self-attention ----
  ln_bf16<<<dim3(NTOK), dim3(256), 0, stream>>>(x, n1w, n1b, Hb);
  gemm2<EPI_BF16><<<dim3(3072 / 128, NTOK / 128), dim3(512), 0, stream>>>(
      Hb, (u16*)(ws + OFF_WSAQKV), (float*)(ws + OFF_BSAQKV), QKV, nullptr, nullptr, nullptr,
      NTOK, 3072, 1024, 1);
  rope_scatter<1, 0><<<dim3(NTOK), dim3(128), 0, stream>>>(QKV, 3072, 0, QR, tcos, tsin, LQ, QSCALE);
  rope_scatter<1, 0><<<dim3(NTOK), dim3(128), 0, stream>>>(QKV, 3072, 1024, KR, tcos, tsin, LQ, 1.0f);
  rope_scatter<0, 1><<<dim3(NTOK), dim3(128), 0, stream>>>(QKV, 3072, 2048, VT, tcos, tsin, LQ, 1.0f);
  flash_attn2<1><<<dim3(512), dim3(256), 0, stream>>>(QR, KR, VT, AO, LQ, LQ);
  gemm2<EPI_RESID><<<dim3(1024 / 128, NTOK / 128), dim3(512), 0, stream>>>(
      AO, (u16*)(ws + OFF_WSAP), sa_pb, nullptr, out, x, g_msa, NTOK, 1024, 1024, 1);

  // ---- cross-attention ----
  ln_bf16<<<dim3(NTOK), dim3(256), 0, stream>>>(out, n2w, n2b, Hb);
  gemm2<EPI_BF16><<<dim3(1024 / 128, NTOK / 128), dim3(512), 0, stream>>>(
      Hb, (u16*)(ws + OFF_WCAQ), ca_qb, (u16*)(ws + OFF_CAQ), nullptr, nullptr, nullptr,
      NTOK, 1024, 1024, 1);
  gemm2<EPI_BF16><<<dim3(2048 / 128, NCTX / 128), dim3(512), 0, stream>>>(
      (u16*)(ws + OFF_CTXB), (u16*)(ws + OFF_WCAKV), (float*)(ws + OFF_BCAKV),
      (u16*)(ws + OFF_CAKV), nullptr, nullptr, nullptr, NCTX, 2048, 1024, 1);
  rope_scatter<1, 0><<<dim3(NTOK), dim3(128), 0, stream>>>((u16*)(ws + OFF_CAQ), 1024, 0, QR, tcos, tsin, LQ, QSCALE);
  rope_scatter<1, 0><<<dim3(NCTX), dim3(128), 0, stream>>>((u16*)(ws + OFF_CAKV), 2048, 0, KR, tcos, tsin, LC, 1.0f);
  rope_scatter<0, 1><<<dim3(NCTX), dim3(128), 0, stream>>>((u16*)(ws + OFF_CAKV), 2048, 1024, VT, tcos, tsin, LC, 1.0f);
  flash_attn2<0><<<dim3(512), dim3(256), 0, stream>>>(QR, KR, VT, AO, LQ, LC);
  gemm2<EPI_RESID><<<dim3(1024 / 128, NTOK / 128), dim3(512), 0, stream>>>(
      AO, (u16*)(ws + OFF_WCAP), ca_pb, nullptr, out, out, g_ca, NTOK, 1024, 1024, 1);

  // ---- MLP ----
  ln_bf16<<<dim3(NTOK), dim3(256), 0, stream>>>(out, n3w, n3b, Hb);
  gemm2<EPI_GELU><<<dim3(4096 / 128, NTOK / 128), dim3(512), 0, stream>>>(
      Hb, (u16*)(ws + OFF_WFC1), fc1b, (u16*)(ws + OFF_U), nullptr, nullptr, nullptr,
      NTOK, 4096, 1024, 1);
  // fc2: split-K x2, atomic accumulation; bias+gate pre-applied
  init_bias_gate<<<dim3(4096), dim3(256), 0, stream>>>(out, fc2b, g_mlp);
  gemm2<EPI_ATOMIC><<<dim3(1024 / 128, NTOK / 128, 2), dim3(512), 0, stream>>>(
      (u16*)(ws + OFF_U), (u16*)(ws + OFF_WFC2), nullptr, nullptr, out, nullptr, g_mlp,
      NTOK, 1024, 4096, 2);
}